// Round 1
// baseline (538.915 us; speedup 1.0000x reference)
//
#include <hip/hip_runtime.h>
#include <hip/hip_bf16.h>

#define B_ 4
#define T_ 2048
#define H_ 16
#define DK_ 64
#define F_ 1024

typedef __bf16 bf16x8 __attribute__((ext_vector_type(8)));
typedef float f32x4 __attribute__((ext_vector_type(4)));

__device__ __forceinline__ void async_cp16(const void* g, void* l) {
  __builtin_amdgcn_global_load_lds((const __attribute__((address_space(1))) void*)g,
                                   (__attribute__((address_space(3))) void*)l, 16, 0, 0);
}

// ---------------- fp32 -> bf16 ----------------
__global__ void cvt_bf16(const float* __restrict__ in, __bf16* __restrict__ out, int n) {
  int i = (blockIdx.x * 256 + threadIdx.x) * 8;
  if (i >= n) return;
  float4 a = *(const float4*)(in + i);
  float4 b = *(const float4*)(in + i + 4);
  bf16x8 o;
  o[0] = (__bf16)a.x; o[1] = (__bf16)a.y; o[2] = (__bf16)a.z; o[3] = (__bf16)a.w;
  o[4] = (__bf16)b.x; o[5] = (__bf16)b.y; o[6] = (__bf16)b.z; o[7] = (__bf16)b.w;
  *(bf16x8*)(out + i) = o;
}

// ---------------- C = A * B^T (+bias) ; A: MxK, B: NxK, both bf16 row-major ----------------
template <int OUT_BF16>
__global__ __launch_bounds__(256) void gemm_bt(
    const __bf16* __restrict__ A, const __bf16* __restrict__ Bm,
    void* __restrict__ Cout, const float* __restrict__ bias,
    int M, int N, int K) {
  __shared__ __bf16 As[128 * 32];
  __shared__ __bf16 Bs[128 * 32];
  const int tid = threadIdx.x;
  const int wave = tid >> 6, lane = tid & 63;
  const int mrow = lane & 15, quad = lane >> 4;
  const long m0 = (long)blockIdx.y * 128, n0 = (long)blockIdx.x * 128;
  const int wr = (wave >> 1) * 64, wc = (wave & 1) * 64;
  const int srow = lane >> 2;        // 0..15
  const int scol = (lane & 3) * 8;   // 0,8,16,24
  f32x4 acc[4][4] = {};
  for (int k0 = 0; k0 < K; k0 += 32) {
    if (k0) __syncthreads();
    for (int ph = 0; ph < 2; ++ph) {
      int rb = ph * 64 + wave * 16;
      async_cp16(A + (m0 + rb + srow) * (long)K + k0 + scol, As + rb * 32);
      async_cp16(Bm + (n0 + rb + srow) * (long)K + k0 + scol, Bs + rb * 32);
    }
    __syncthreads();
    bf16x8 af[4], bf[4];
    for (int i = 0; i < 4; i++) af[i] = *(const bf16x8*)&As[(wr + i * 16 + mrow) * 32 + quad * 8];
    for (int j = 0; j < 4; j++) bf[j] = *(const bf16x8*)&Bs[(wc + j * 16 + mrow) * 32 + quad * 8];
    for (int i = 0; i < 4; i++)
      for (int j = 0; j < 4; j++)
        acc[i][j] = __builtin_amdgcn_mfma_f32_16x16x32_bf16(af[i], bf[j], acc[i][j], 0, 0, 0);
  }
  for (int i = 0; i < 4; i++) {
    int row = (int)m0 + wr + i * 16 + quad * 4;
    for (int j = 0; j < 4; j++) {
      int col = (int)n0 + wc + j * 16 + mrow;
      float bval = bias ? bias[col] : 0.f;
      for (int r = 0; r < 4; r++) {
        float v = acc[i][j][r] + bval;
        if (OUT_BF16)
          ((__bf16*)Cout)[(long)(row + r) * N + col] = (__bf16)v;
        else
          ((float*)Cout)[(long)(row + r) * N + col] = v;
      }
    }
  }
}

// ---------------- K' = K + P (in place), bias[b,h,s] = u.K + vb.P ----------------
__global__ void kp_bias(__bf16* __restrict__ Kb, const __bf16* __restrict__ Pb,
                        const float* __restrict__ u, const float* __restrict__ vb,
                        float* __restrict__ biasC) {
  int gw = blockIdx.x * 4 + (threadIdx.x >> 6);  // (b*T + t)*H + h
  int lane = threadIdx.x & 63;
  int h = gw & 15;
  int t = (gw >> 4) & 2047;
  int b = gw >> 15;
  long kidx = (long)gw * 64 + lane;
  float kv = (float)Kb[kidx];
  float pv = (float)Pb[((long)t * 16 + h) * 64 + lane];
  Kb[kidx] = (__bf16)(kv + pv);
  float s = kv * u[h * 64 + lane] + pv * vb[h * 64 + lane];
  for (int d = 1; d < 64; d <<= 1) s += __shfl_xor(s, d);
  if (lane == 0) biasC[((long)(b * 16 + h)) * 2048 + t] = s;
}

// ---------------- banded flash attention ----------------
__global__ __launch_bounds__(256) void attn_banded(
    const __bf16* __restrict__ Q, const __bf16* __restrict__ Kp,
    const __bf16* __restrict__ V, const float* __restrict__ biasC,
    __bf16* __restrict__ X) {
  constexpr int LD = 72;  // 64 + 8 pad: conflict-free b128 LDS reads
  __shared__ __bf16 Qs[64 * LD];
  __shared__ __bf16 Ks[64 * LD];
  __shared__ __bf16 Vt[64 * LD];
  __shared__ __bf16 Pl[64 * LD];
  const int qc = blockIdx.x, h = blockIdx.y, b = blockIdx.z;
  const int tid = threadIdx.x, wave = tid >> 6, lane = tid & 63;
  const int mrow = lane & 15, quad = lane >> 4;
  const int r4 = tid >> 2, c16 = (tid & 3) * 16;
  {  // stage Q chunk
    const __bf16* src = Q + ((long)(b * T_ + qc * 64 + r4) * H_ + h) * DK_ + c16;
    bf16x8 v0 = *(const bf16x8*)src;
    bf16x8 v1 = *(const bf16x8*)(src + 8);
    *(bf16x8*)&Qs[r4 * LD + c16] = v0;
    *(bf16x8*)&Qs[r4 * LD + c16 + 8] = v1;
  }
  f32x4 accO[4] = {};
  float m_run[4] = {-1e30f, -1e30f, -1e30f, -1e30f};
  float l_run[4] = {0.f, 0.f, 0.f, 0.f};
  const int kc0 = qc >= 16 ? qc - 16 : 0;
  for (int kc = kc0; kc <= qc; ++kc) {
    __syncthreads();  // previous-iter readers done (also publishes Qs on first iter)
    {  // stage K' chunk and V chunk (V transposed: Vt[dk][s])
      const __bf16* ksrc = Kp + ((long)(b * T_ + kc * 64 + r4) * H_ + h) * DK_ + c16;
      bf16x8 k0v = *(const bf16x8*)ksrc;
      bf16x8 k1v = *(const bf16x8*)(ksrc + 8);
      *(bf16x8*)&Ks[r4 * LD + c16] = k0v;
      *(bf16x8*)&Ks[r4 * LD + c16 + 8] = k1v;
      const __bf16* vsrc = V + ((long)(b * T_ + kc * 64 + r4) * H_ + h) * DK_ + c16;
      bf16x8 vv0 = *(const bf16x8*)vsrc;
      bf16x8 vv1 = *(const bf16x8*)(vsrc + 8);
      for (int j = 0; j < 8; j++) Vt[(c16 + j) * LD + r4] = vv0[j];
      for (int j = 0; j < 8; j++) Vt[(c16 + 8 + j) * LD + r4] = vv1[j];
    }
    __syncthreads();
    // S = Q K'^T  (this wave's 16 query rows x 64 keys)
    bf16x8 aq0 = *(const bf16x8*)&Qs[(wave * 16 + mrow) * LD + quad * 8];
    bf16x8 aq1 = *(const bf16x8*)&Qs[(wave * 16 + mrow) * LD + 32 + quad * 8];
    f32x4 s[4] = {};
    for (int j = 0; j < 4; j++) {
      bf16x8 bk0 = *(const bf16x8*)&Ks[(j * 16 + mrow) * LD + quad * 8];
      bf16x8 bk1 = *(const bf16x8*)&Ks[(j * 16 + mrow) * LD + 32 + quad * 8];
      s[j] = __builtin_amdgcn_mfma_f32_16x16x32_bf16(aq0, bk0, s[j], 0, 0, 0);
      s[j] = __builtin_amdgcn_mfma_f32_16x16x32_bf16(aq1, bk1, s[j], 0, 0, 0);
    }
    const float* bptr = biasC + ((long)(b * H_ + h)) * T_ + kc * 64;
    float sv[4][4];
    for (int j = 0; j < 4; j++) {
      float bj = bptr[j * 16 + mrow];
      for (int r = 0; r < 4; r++) sv[j][r] = (s[j][r] + bj) * 0.125f;
    }
    // online softmax per query row (rows = quad*4+r, cols distributed over 16 lanes x 4 tiles)
    for (int r = 0; r < 4; r++) {
      float mx = fmaxf(fmaxf(sv[0][r], sv[1][r]), fmaxf(sv[2][r], sv[3][r]));
      for (int d = 1; d < 16; d <<= 1) mx = fmaxf(mx, __shfl_xor(mx, d));
      float mnew = fmaxf(m_run[r], mx);
      float alpha = __expf(m_run[r] - mnew);
      m_run[r] = mnew;
      float psum = 0.f;
      for (int j = 0; j < 4; j++) {
        float p = __expf(sv[j][r] - mnew);
        psum += p;
        Pl[(wave * 16 + quad * 4 + r) * LD + j * 16 + mrow] = (__bf16)p;
      }
      for (int d = 1; d < 16; d <<= 1) psum += __shfl_xor(psum, d);
      l_run[r] = l_run[r] * alpha + psum;
      accO[0][r] *= alpha; accO[1][r] *= alpha; accO[2][r] *= alpha; accO[3][r] *= alpha;
    }
    // P (C-layout) -> A-layout via per-wave LDS round trip; O += P * V
    bf16x8 ap0 = *(const bf16x8*)&Pl[(wave * 16 + mrow) * LD + quad * 8];
    bf16x8 ap1 = *(const bf16x8*)&Pl[(wave * 16 + mrow) * LD + 32 + quad * 8];
    for (int n = 0; n < 4; n++) {
      bf16x8 bv0 = *(const bf16x8*)&Vt[(n * 16 + mrow) * LD + quad * 8];
      bf16x8 bv1 = *(const bf16x8*)&Vt[(n * 16 + mrow) * LD + 32 + quad * 8];
      accO[n] = __builtin_amdgcn_mfma_f32_16x16x32_bf16(ap0, bv0, accO[n], 0, 0, 0);
      accO[n] = __builtin_amdgcn_mfma_f32_16x16x32_bf16(ap1, bv1, accO[n], 0, 0, 0);
    }
  }
  for (int r = 0; r < 4; r++) {
    float inv = 1.0f / l_run[r];
    int t = qc * 64 + wave * 16 + quad * 4 + r;
    for (int n = 0; n < 4; n++)
      X[((long)(b * T_ + t) * H_ + h) * DK_ + n * 16 + mrow] = (__bf16)(accO[n][r] * inv);
  }
}

extern "C" void kernel_launch(void* const* d_in, const int* in_sizes, int n_in,
                              void* d_out, int out_size, void* d_ws, size_t ws_size,
                              hipStream_t stream) {
  (void)in_sizes; (void)n_in; (void)out_size; (void)ws_size;
  const float* query = (const float*)d_in[0];
  const float* key   = (const float*)d_in[1];
  const float* value = (const float*)d_in[2];
  const float* pos   = (const float*)d_in[3];
  // d_in[4] = mask: chunk structure is computed analytically, not read
  const float* Wq = (const float*)d_in[5];
  const float* bq = (const float*)d_in[6];
  const float* Wk = (const float*)d_in[7];
  const float* bk = (const float*)d_in[8];
  const float* Wv = (const float*)d_in[9];
  const float* bv = (const float*)d_in[10];
  const float* Wp = (const float*)d_in[11];
  const float* Wo = (const float*)d_in[12];
  const float* bo = (const float*)d_in[13];
  const float* pu = (const float*)d_in[14];
  const float* pvb = (const float*)d_in[15];

  const long NQ = (long)B_ * T_ * F_;  // 8388608
  const long NP = (long)T_ * F_;       // 2097152
  const long NW = (long)F_ * F_;       // 1048576
  char* ws = (char*)d_ws;
  __bf16* qb  = (__bf16*)ws; ws += NQ * 2;
  __bf16* kb  = (__bf16*)ws; ws += NQ * 2;
  __bf16* vbm = (__bf16*)ws; ws += NQ * 2;
  __bf16* pb  = (__bf16*)ws; ws += NP * 2;
  __bf16* wqb = (__bf16*)ws; ws += NW * 2;
  __bf16* wkb = (__bf16*)ws; ws += NW * 2;
  __bf16* wvb = (__bf16*)ws; ws += NW * 2;
  __bf16* wpb = (__bf16*)ws; ws += NW * 2;
  __bf16* wob = (__bf16*)ws; ws += NW * 2;
  __bf16* Qb  = (__bf16*)ws; ws += NQ * 2;
  __bf16* Kb  = (__bf16*)ws; ws += NQ * 2;
  __bf16* Vb  = (__bf16*)ws; ws += NQ * 2;
  __bf16* Pb  = (__bf16*)ws; ws += NP * 2;
  float*  biasC = (float*)ws; ws += (long)B_ * H_ * T_ * 4;
  __bf16* Xb  = (__bf16*)ws; ws += NQ * 2;

  cvt_bf16<<<NQ / 8 / 256, 256, 0, stream>>>(query, qb, (int)NQ);
  cvt_bf16<<<NQ / 8 / 256, 256, 0, stream>>>(key, kb, (int)NQ);
  cvt_bf16<<<NQ / 8 / 256, 256, 0, stream>>>(value, vbm, (int)NQ);
  cvt_bf16<<<NP / 8 / 256, 256, 0, stream>>>(pos, pb, (int)NP);
  cvt_bf16<<<NW / 8 / 256, 256, 0, stream>>>(Wq, wqb, (int)NW);
  cvt_bf16<<<NW / 8 / 256, 256, 0, stream>>>(Wk, wkb, (int)NW);
  cvt_bf16<<<NW / 8 / 256, 256, 0, stream>>>(Wv, wvb, (int)NW);
  cvt_bf16<<<NW / 8 / 256, 256, 0, stream>>>(Wp, wpb, (int)NW);
  cvt_bf16<<<NW / 8 / 256, 256, 0, stream>>>(Wo, wob, (int)NW);

  dim3 g1(F_ / 128, (B_ * T_) / 128);  // (8, 64)
  gemm_bt<1><<<g1, 256, 0, stream>>>(qb, wqb, Qb, bq, B_ * T_, F_, F_);
  gemm_bt<1><<<g1, 256, 0, stream>>>(kb, wkb, Kb, bk, B_ * T_, F_, F_);
  gemm_bt<1><<<g1, 256, 0, stream>>>(vbm, wvb, Vb, bv, B_ * T_, F_, F_);
  dim3 g2(F_ / 128, T_ / 128);  // (8, 16)
  gemm_bt<1><<<g2, 256, 0, stream>>>(pb, wpb, Pb, nullptr, T_, F_, F_);

  kp_bias<<<(B_ * T_ * H_) / 4, 256, 0, stream>>>(Kb, Pb, pu, pvb, biasC);

  attn_banded<<<dim3(T_ / 64, H_, B_), 256, 0, stream>>>(Qb, Kb, Vb, biasC, Xb);

  gemm_bt<0><<<g1, 256, 0, stream>>>(Xb, wob, d_out, bo, B_ * T_, F_, F_);
}

// Round 3
// 454.849 us; speedup vs baseline: 1.1848x; 1.1848x over previous
//
#include <hip/hip_runtime.h>
#include <hip/hip_bf16.h>

#define B_ 4
#define T_ 2048
#define H_ 16
#define DK_ 64
#define F_ 1024
// (1/sqrt(DK)) * log2(e): softmax computed in exp2 domain (1 v_exp_f32 per key)
#define SCALE_LOG2 0.18033688011112042f

typedef __bf16 bf16x8 __attribute__((ext_vector_type(8)));
typedef float f32x4 __attribute__((ext_vector_type(4)));

__device__ __forceinline__ void async_cp16(const void* g, void* l) {
  __builtin_amdgcn_global_load_lds((const __attribute__((address_space(1))) void*)g,
                                   (__attribute__((address_space(3))) void*)l, 16, 0, 0);
}

// ---------------- fused fp32 -> bf16 for all 9 tensors ----------------
struct CvtArgs {
  const float* src[9];
  __bf16* dst[9];
  int n[9];
};
__global__ void cvt_all(CvtArgs a) {
  int t = blockIdx.y;
  int i = (blockIdx.x * 256 + threadIdx.x) * 8;
  if (i >= a.n[t]) return;
  const float* in = a.src[t];
  __bf16* out = a.dst[t];
  float4 x = *(const float4*)(in + i);
  float4 y = *(const float4*)(in + i + 4);
  bf16x8 o;
  o[0] = (__bf16)x.x; o[1] = (__bf16)x.y; o[2] = (__bf16)x.z; o[3] = (__bf16)x.w;
  o[4] = (__bf16)y.x; o[5] = (__bf16)y.y; o[6] = (__bf16)y.z; o[7] = (__bf16)y.w;
  *(bf16x8*)(out + i) = o;
}

// ---------------- fused QKVP GEMM: out = A * W^T (+bias), stored head-major ----------------
// z = 0..3 selects (A, W, bias, out, Mblocks). Out layout: [b][h][t][d] (P: [h][t][d]).
struct GemmQKVP {
  const __bf16* A[4];
  const __bf16* W[4];
  const float* bias[4];
  __bf16* out[4];
  int Mblocks[4];
};
__global__ __launch_bounds__(256) void gemm_qkvp(GemmQKVP g) {
  const int z = blockIdx.z;
  if ((int)blockIdx.y >= g.Mblocks[z]) return;
  const __bf16* __restrict__ A = g.A[z];
  const __bf16* __restrict__ Bm = g.W[z];
  const float* __restrict__ bias = g.bias[z];
  __bf16* __restrict__ Cout = g.out[z];
  constexpr int K = F_;
  __shared__ __bf16 As[128 * 32];
  __shared__ __bf16 Bs[128 * 32];
  const int tid = threadIdx.x;
  const int wave = tid >> 6, lane = tid & 63;
  const int mrow = lane & 15, quad = lane >> 4;
  const long m0 = (long)blockIdx.y * 128, n0 = (long)blockIdx.x * 128;
  const int wr = (wave >> 1) * 64, wc = (wave & 1) * 64;
  const int srow = lane >> 2;
  const int scol = (lane & 3) * 8;
  f32x4 acc[4][4] = {};
  for (int k0 = 0; k0 < K; k0 += 32) {
    if (k0) __syncthreads();
    for (int ph = 0; ph < 2; ++ph) {
      int rb = ph * 64 + wave * 16;
      async_cp16(A + (m0 + rb + srow) * (long)K + k0 + scol, As + rb * 32);
      async_cp16(Bm + (n0 + rb + srow) * (long)K + k0 + scol, Bs + rb * 32);
    }
    __syncthreads();
    bf16x8 af[4], bf[4];
    for (int i = 0; i < 4; i++) af[i] = *(const bf16x8*)&As[(wr + i * 16 + mrow) * 32 + quad * 8];
    for (int j = 0; j < 4; j++) bf[j] = *(const bf16x8*)&Bs[(wc + j * 16 + mrow) * 32 + quad * 8];
    for (int i = 0; i < 4; i++)
      for (int j = 0; j < 4; j++)
        acc[i][j] = __builtin_amdgcn_mfma_f32_16x16x32_bf16(af[i], bf[j], acc[i][j], 0, 0, 0);
  }
  for (int i = 0; i < 4; i++) {
    int row0 = (int)m0 + wr + i * 16 + quad * 4;
    for (int j = 0; j < 4; j++) {
      int col = (int)n0 + wc + j * 16 + mrow;
      float bval = bias ? bias[col] : 0.f;
      int h = col >> 6, d = col & 63;
      for (int r = 0; r < 4; r++) {
        int row = row0 + r;
        int b = row >> 11, t = row & 2047;
        long idx = (((long)(b * H_ + h)) * T_ + t) * DK_ + d;
        Cout[idx] = (__bf16)(acc[i][j][r] + bval);
      }
    }
  }
}

// ---------------- plain C = A * B^T + bias, fp32 out (final projection) ----------------
__global__ __launch_bounds__(256) void gemm_out(
    const __bf16* __restrict__ A, const __bf16* __restrict__ Bm,
    float* __restrict__ Cout, const float* __restrict__ bias, int N, int K) {
  __shared__ __bf16 As[128 * 32];
  __shared__ __bf16 Bs[128 * 32];
  const int tid = threadIdx.x;
  const int wave = tid >> 6, lane = tid & 63;
  const int mrow = lane & 15, quad = lane >> 4;
  const long m0 = (long)blockIdx.y * 128, n0 = (long)blockIdx.x * 128;
  const int wr = (wave >> 1) * 64, wc = (wave & 1) * 64;
  const int srow = lane >> 2;
  const int scol = (lane & 3) * 8;
  f32x4 acc[4][4] = {};
  for (int k0 = 0; k0 < K; k0 += 32) {
    if (k0) __syncthreads();
    for (int ph = 0; ph < 2; ++ph) {
      int rb = ph * 64 + wave * 16;
      async_cp16(A + (m0 + rb + srow) * (long)K + k0 + scol, As + rb * 32);
      async_cp16(Bm + (n0 + rb + srow) * (long)K + k0 + scol, Bs + rb * 32);
    }
    __syncthreads();
    bf16x8 af[4], bf[4];
    for (int i = 0; i < 4; i++) af[i] = *(const bf16x8*)&As[(wr + i * 16 + mrow) * 32 + quad * 8];
    for (int j = 0; j < 4; j++) bf[j] = *(const bf16x8*)&Bs[(wc + j * 16 + mrow) * 32 + quad * 8];
    for (int i = 0; i < 4; i++)
      for (int j = 0; j < 4; j++)
        acc[i][j] = __builtin_amdgcn_mfma_f32_16x16x32_bf16(af[i], bf[j], acc[i][j], 0, 0, 0);
  }
  for (int i = 0; i < 4; i++) {
    int row = (int)m0 + wr + i * 16 + quad * 4;
    for (int j = 0; j < 4; j++) {
      int col = (int)n0 + wc + j * 16 + mrow;
      float bval = bias[col];
      for (int r = 0; r < 4; r++)
        Cout[(long)(row + r) * N + col] = acc[i][j][r] + bval;
    }
  }
}

// ---------------- prep: K' = K + P, biasC = (u.K + v.P)*SCALE_LOG2, Vt = V^T ----------------
__global__ __launch_bounds__(256) void prep(
    const __bf16* __restrict__ Ph, __bf16* __restrict__ Kh,
    const __bf16* __restrict__ Vh, __bf16* __restrict__ Vth,
    const float* __restrict__ u, const float* __restrict__ vb,
    float* __restrict__ biasC) {
  __shared__ __bf16 Vl[64 * 72];
  const int tc = blockIdx.x, h = blockIdx.y, b = blockIdx.z;
  const int tid = threadIdx.x;
  const int r4 = tid >> 2, c16 = (tid & 3) * 16;
  const long bh = b * H_ + h;
  const long kbase = (bh * T_ + tc * 64 + r4) * DK_ + c16;
  const long pbase = (((long)h) * T_ + tc * 64 + r4) * DK_ + c16;
  bf16x8 k0 = *(const bf16x8*)&Kh[kbase];
  bf16x8 k1 = *(const bf16x8*)&Kh[kbase + 8];
  bf16x8 p0 = *(const bf16x8*)&Ph[pbase];
  bf16x8 p1 = *(const bf16x8*)&Ph[pbase + 8];
  float4 u0 = *(const float4*)&u[h * 64 + c16];
  float4 u1 = *(const float4*)&u[h * 64 + c16 + 4];
  float4 u2 = *(const float4*)&u[h * 64 + c16 + 8];
  float4 u3 = *(const float4*)&u[h * 64 + c16 + 12];
  float4 v0 = *(const float4*)&vb[h * 64 + c16];
  float4 v1 = *(const float4*)&vb[h * 64 + c16 + 4];
  float4 v2 = *(const float4*)&vb[h * 64 + c16 + 8];
  float4 v3 = *(const float4*)&vb[h * 64 + c16 + 12];
  float s = 0.f;
  {
    const float uu[16] = {u0.x,u0.y,u0.z,u0.w,u1.x,u1.y,u1.z,u1.w,u2.x,u2.y,u2.z,u2.w,u3.x,u3.y,u3.z,u3.w};
    const float vv[16] = {v0.x,v0.y,v0.z,v0.w,v1.x,v1.y,v1.z,v1.w,v2.x,v2.y,v2.z,v2.w,v3.x,v3.y,v3.z,v3.w};
#pragma unroll
    for (int j = 0; j < 8; j++) {
      s += (float)k0[j] * uu[j] + (float)p0[j] * vv[j];
      s += (float)k1[j] * uu[8 + j] + (float)p1[j] * vv[8 + j];
    }
  }
  // K' = K + P, store back
  bf16x8 kp0, kp1;
#pragma unroll
  for (int j = 0; j < 8; j++) {
    kp0[j] = (__bf16)((float)k0[j] + (float)p0[j]);
    kp1[j] = (__bf16)((float)k1[j] + (float)p1[j]);
  }
  *(bf16x8*)&Kh[kbase] = kp0;
  *(bf16x8*)&Kh[kbase + 8] = kp1;
  s += __shfl_xor(s, 1);
  s += __shfl_xor(s, 2);
  if ((tid & 3) == 0) biasC[bh * T_ + tc * 64 + r4] = s * SCALE_LOG2;
  // V transpose via LDS
  const long vbase = (bh * T_ + tc * 64 + r4) * DK_ + c16;
  bf16x8 vv0 = *(const bf16x8*)&Vh[vbase];
  bf16x8 vv1 = *(const bf16x8*)&Vh[vbase + 8];
  *(bf16x8*)&Vl[r4 * 72 + c16] = vv0;
  *(bf16x8*)&Vl[r4 * 72 + c16 + 8] = vv1;
  __syncthreads();
  const int d4 = tid >> 2, tcol = (tid & 3) * 16;
  bf16x8 o0, o1;
#pragma unroll
  for (int j = 0; j < 8; j++) {
    o0[j] = Vl[(tcol + j) * 72 + d4];
    o1[j] = Vl[(tcol + 8 + j) * 72 + d4];
  }
  long obase = (bh * DK_ + d4) * T_ + tc * 64 + tcol;
  *(bf16x8*)&Vth[obase] = o0;
  *(bf16x8*)&Vth[obase + 8] = o1;
}

// ---------------- banded flash attention, 128-key tiles ----------------
template <int NT>  // number of 16-key tiles per iteration (4 or 8)
__device__ __forceinline__ void attn_step(
    int s0, long bh, int tid, int wave, int mrow, int quad,
    const __bf16* __restrict__ Kh, const __bf16* __restrict__ Vth,
    const float* __restrict__ Bp,
    __bf16* Qs, __bf16* Ks, __bf16* Vt, __bf16* Pl,
    f32x4 accO[4], float m_run[4], float l_run[4]) {
  __syncthreads();  // previous-iter LDS readers done (first call: publishes Qs)
  // stage K' (NT*16 rows x 64 cols) and Vt (64 rows x NT*16 cols), coalesced b128
#pragma unroll
  for (int q = 0; q < NT / 2; ++q) {
    int row = (tid >> 3) + q * 32;
    int off = (tid & 7) * 8;
    *(bf16x8*)&Ks[row * 72 + off] = *(const bf16x8*)&Kh[(bh * T_ + s0 + row) * DK_ + off];
  }
#pragma unroll
  for (int q = 0; q < NT / 2; ++q) {
    int d, off;
    if (NT == 8) { d = (tid >> 4) + q * 16; off = (tid & 15) * 8; }
    else         { d = (tid >> 3) + q * 32; off = (tid & 7) * 8; }
    *(bf16x8*)&Vt[d * 136 + off] = *(const bf16x8*)&Vth[(bh * DK_ + d) * T_ + s0 + off];
  }
  __syncthreads();
  // S = Q K'^T (this wave's 16 query rows)
  bf16x8 aq0 = *(const bf16x8*)&Qs[(wave * 16 + mrow) * 72 + quad * 8];
  bf16x8 aq1 = *(const bf16x8*)&Qs[(wave * 16 + mrow) * 72 + 32 + quad * 8];
  f32x4 s[NT];
#pragma unroll
  for (int j = 0; j < NT; j++) {
    s[j] = (f32x4){0.f, 0.f, 0.f, 0.f};
    bf16x8 bk0 = *(const bf16x8*)&Ks[(j * 16 + mrow) * 72 + quad * 8];
    bf16x8 bk1 = *(const bf16x8*)&Ks[(j * 16 + mrow) * 72 + 32 + quad * 8];
    s[j] = __builtin_amdgcn_mfma_f32_16x16x32_bf16(aq0, bk0, s[j], 0, 0, 0);
    s[j] = __builtin_amdgcn_mfma_f32_16x16x32_bf16(aq1, bk1, s[j], 0, 0, 0);
  }
  // scale + bias (bias already in exp2 domain, per key position)
#pragma unroll
  for (int j = 0; j < NT; j++) {
    float bj = Bp[s0 + j * 16 + mrow];
#pragma unroll
    for (int r = 0; r < 4; r++) s[j][r] = s[j][r] * SCALE_LOG2 + bj;
  }
  // online softmax; rows = quad*4+r, cols spread over 16 lanes x NT tiles
#pragma unroll
  for (int r = 0; r < 4; r++) {
    float mx = s[0][r];
#pragma unroll
    for (int j = 1; j < NT; j++) mx = fmaxf(mx, s[j][r]);
    for (int d = 1; d < 16; d <<= 1) mx = fmaxf(mx, __shfl_xor(mx, d));
    float mnew = fmaxf(m_run[r], mx);
    float alpha = __builtin_amdgcn_exp2f(m_run[r] - mnew);
    m_run[r] = mnew;
    float psum = 0.f;
#pragma unroll
    for (int j = 0; j < NT; j++) {
      float p = __builtin_amdgcn_exp2f(s[j][r] - mnew);
      psum += p;
      Pl[(wave * 16 + quad * 4 + r) * 136 + j * 16 + mrow] = (__bf16)p;
    }
    for (int d = 1; d < 16; d <<= 1) psum += __shfl_xor(psum, d);
    l_run[r] = l_run[r] * alpha + psum;
    accO[0][r] *= alpha; accO[1][r] *= alpha; accO[2][r] *= alpha; accO[3][r] *= alpha;
  }
  // O += P * V (P read back in A layout; Vt in B layout)
  bf16x8 ap[NT / 2];
#pragma unroll
  for (int kt = 0; kt < NT / 2; kt++)
    ap[kt] = *(const bf16x8*)&Pl[(wave * 16 + mrow) * 136 + kt * 32 + quad * 8];
#pragma unroll
  for (int n = 0; n < 4; n++) {
#pragma unroll
    for (int kt = 0; kt < NT / 2; kt++) {
      bf16x8 bv = *(const bf16x8*)&Vt[(n * 16 + mrow) * 136 + kt * 32 + quad * 8];
      accO[n] = __builtin_amdgcn_mfma_f32_16x16x32_bf16(ap[kt], bv, accO[n], 0, 0, 0);
    }
  }
}

__global__ __launch_bounds__(256) void attn_banded(
    const __bf16* __restrict__ Qh, const __bf16* __restrict__ Kh,
    const __bf16* __restrict__ Vth, const float* __restrict__ biasC,
    __bf16* __restrict__ X) {
  __shared__ __bf16 Qs[64 * 72];     //  9216 B
  __shared__ __bf16 Ks[128 * 72];    // 18432 B
  __shared__ __bf16 Vt[64 * 136];    // 17408 B
  __shared__ __bf16 Pl[64 * 136];    // 17408 B  -> total 62464 B
  const int qc = blockIdx.x, h = blockIdx.y, b = blockIdx.z;
  const int tid = threadIdx.x, wave = tid >> 6, lane = tid & 63;
  const int mrow = lane & 15, quad = lane >> 4;
  const long bh = b * H_ + h;
  const int kc0 = qc >= 16 ? qc - 16 : 0;
  const int s_lo = kc0 * 64, s_hi = (qc + 1) * 64;
  const float* Bp = biasC + bh * T_;
  {  // stage Q chunk (coalesced from head-major layout)
    int r4 = tid >> 2, c16 = (tid & 3) * 16;
    const __bf16* src = Qh + (bh * T_ + qc * 64 + r4) * DK_ + c16;
    *(bf16x8*)&Qs[r4 * 72 + c16] = *(const bf16x8*)src;
    *(bf16x8*)&Qs[r4 * 72 + c16 + 8] = *(const bf16x8*)(src + 8);
  }
  f32x4 accO[4] = {};
  float m_run[4] = {-1e30f, -1e30f, -1e30f, -1e30f};
  float l_run[4] = {0.f, 0.f, 0.f, 0.f};
  int s0 = s_lo;
  if ((((s_hi - s_lo) >> 6) & 1)) {
    attn_step<4>(s0, bh, tid, wave, mrow, quad, Kh, Vth, Bp, Qs, Ks, Vt, Pl, accO, m_run, l_run);
    s0 += 64;
  }
  for (; s0 < s_hi; s0 += 128)
    attn_step<8>(s0, bh, tid, wave, mrow, quad, Kh, Vth, Bp, Qs, Ks, Vt, Pl, accO, m_run, l_run);
#pragma unroll
  for (int r = 0; r < 4; r++) {
    float inv = 1.0f / l_run[r];
    int t = qc * 64 + wave * 16 + quad * 4 + r;
#pragma unroll
    for (int n = 0; n < 4; n++)
      X[((long)(b * T_ + t) * H_ + h) * DK_ + n * 16 + mrow] = (__bf16)(accO[n][r] * inv);
  }
}

extern "C" void kernel_launch(void* const* d_in, const int* in_sizes, int n_in,
                              void* d_out, int out_size, void* d_ws, size_t ws_size,
                              hipStream_t stream) {
  (void)in_sizes; (void)n_in; (void)out_size; (void)ws_size;
  const float* query = (const float*)d_in[0];
  const float* key   = (const float*)d_in[1];
  const float* value = (const float*)d_in[2];
  const float* pos   = (const float*)d_in[3];
  // d_in[4] = mask: band structure computed analytically
  const float* Wq = (const float*)d_in[5];
  const float* bq = (const float*)d_in[6];
  const float* Wk = (const float*)d_in[7];
  const float* bk = (const float*)d_in[8];
  const float* Wv = (const float*)d_in[9];
  const float* bv = (const float*)d_in[10];
  const float* Wp = (const float*)d_in[11];
  const float* Wo = (const float*)d_in[12];
  const float* bo = (const float*)d_in[13];
  const float* pu = (const float*)d_in[14];
  const float* pvb = (const float*)d_in[15];

  const long NQ = (long)B_ * T_ * F_;  // 8388608
  const long NP = (long)T_ * F_;       // 2097152
  const long NW = (long)F_ * F_;       // 1048576
  char* ws = (char*)d_ws;
  __bf16* qb  = (__bf16*)ws; ws += NQ * 2;
  __bf16* kb  = (__bf16*)ws; ws += NQ * 2;
  __bf16* vbm = (__bf16*)ws; ws += NQ * 2;
  __bf16* pb  = (__bf16*)ws; ws += NP * 2;
  __bf16* wqb = (__bf16*)ws; ws += NW * 2;
  __bf16* wkb = (__bf16*)ws; ws += NW * 2;
  __bf16* wvb = (__bf16*)ws; ws += NW * 2;
  __bf16* wpb = (__bf16*)ws; ws += NW * 2;
  __bf16* wob = (__bf16*)ws; ws += NW * 2;
  __bf16* Qh  = (__bf16*)ws; ws += NQ * 2;
  __bf16* Kh  = (__bf16*)ws; ws += NQ * 2;
  __bf16* Vh  = (__bf16*)ws; ws += NQ * 2;
  __bf16* Ph  = (__bf16*)ws; ws += NP * 2;
  float*  biasC = (float*)ws; ws += (long)B_ * H_ * T_ * 4;
  __bf16* Vth = kb;  // alias: kb dead after K-GEMM
  __bf16* Xb  = qb;  // alias: qb dead after Q-GEMM

  {
    CvtArgs ca;
    ca.src[0] = query; ca.dst[0] = qb;  ca.n[0] = (int)NQ;
    ca.src[1] = key;   ca.dst[1] = kb;  ca.n[1] = (int)NQ;
    ca.src[2] = value; ca.dst[2] = vbm; ca.n[2] = (int)NQ;
    ca.src[3] = pos;   ca.dst[3] = pb;  ca.n[3] = (int)NP;
    ca.src[4] = Wq;    ca.dst[4] = wqb; ca.n[4] = (int)NW;
    ca.src[5] = Wk;    ca.dst[5] = wkb; ca.n[5] = (int)NW;
    ca.src[6] = Wv;    ca.dst[6] = wvb; ca.n[6] = (int)NW;
    ca.src[7] = Wp;    ca.dst[7] = wpb; ca.n[7] = (int)NW;
    ca.src[8] = Wo;    ca.dst[8] = wob; ca.n[8] = (int)NW;
    cvt_all<<<dim3(4096, 9), 256, 0, stream>>>(ca);
  }
  {
    GemmQKVP g;
    g.A[0] = qb;  g.W[0] = wqb; g.bias[0] = bq;      g.out[0] = Qh; g.Mblocks[0] = 64;
    g.A[1] = kb;  g.W[1] = wkb; g.bias[1] = bk;      g.out[1] = Kh; g.Mblocks[1] = 64;
    g.A[2] = vbm; g.W[2] = wvb; g.bias[2] = bv;      g.out[2] = Vh; g.Mblocks[2] = 64;
    g.A[3] = pb;  g.W[3] = wpb; g.bias[3] = nullptr; g.out[3] = Ph; g.Mblocks[3] = 16;
    gemm_qkvp<<<dim3(8, 64, 4), 256, 0, stream>>>(g);
  }
  prep<<<dim3(32, 16, 4), 256, 0, stream>>>(Ph, Kh, Vh, Vth, pu, pvb, biasC);
  attn_banded<<<dim3(32, 16, 4), 256, 0, stream>>>(Qh, Kh, Vth, biasC, Xb);
  gemm_out<<<dim3(8, 64), 256, 0, stream>>>(Xb, wob, (float*)d_out, bo, F_, F_);
}

// Round 4
// 422.860 us; speedup vs baseline: 1.2745x; 1.0757x over previous
//
#include <hip/hip_runtime.h>
#include <hip/hip_bf16.h>

#define B_ 4
#define T_ 2048
#define H_ 16
#define DK_ 64
#define F_ 1024
// (1/sqrt(DK)) * log2(e): softmax computed in exp2 domain
#define SCALE_LOG2 0.18033688011112042f

typedef __bf16 bf16x8 __attribute__((ext_vector_type(8)));
typedef __bf16 bf16x4 __attribute__((ext_vector_type(4)));
typedef float f32x4 __attribute__((ext_vector_type(4)));

__device__ __forceinline__ void async_cp16(const void* g, void* l) {
  __builtin_amdgcn_global_load_lds((const __attribute__((address_space(1))) void*)g,
                                   (__attribute__((address_space(3))) void*)l, 16, 0, 0);
}

// ---------------- fused fp32 -> bf16 for all 9 tensors ----------------
struct CvtArgs {
  const float* src[9];
  __bf16* dst[9];
  int n[9];
};
__global__ void cvt_all(CvtArgs a) {
  int t = blockIdx.y;
  int i = (blockIdx.x * 256 + threadIdx.x) * 8;
  if (i >= a.n[t]) return;
  const float* in = a.src[t];
  __bf16* out = a.dst[t];
  float4 x = *(const float4*)(in + i);
  float4 y = *(const float4*)(in + i + 4);
  bf16x8 o;
  o[0] = (__bf16)x.x; o[1] = (__bf16)x.y; o[2] = (__bf16)x.z; o[3] = (__bf16)x.w;
  o[4] = (__bf16)y.x; o[5] = (__bf16)y.y; o[6] = (__bf16)y.z; o[7] = (__bf16)y.w;
  *(bf16x8*)(out + i) = o;
}

// ---------------- fused QKVP GEMM (transposed): D[f][token] = W * Act^T ----------------
// A = W (1024 x K), B = activations (tokens x K). C-layout reg r runs along f (=d),
// so head-major stores are packed 8B bf16x4 per acc tile. Out: [b][h][t][d] (P: [h][t][d]).
struct GemmQKVP {
  const __bf16* W[4];
  const __bf16* Act[4];
  const float* bias[4];
  __bf16* out[4];
  int Nblocks[4];  // token-blocks
};
__global__ __launch_bounds__(256) void gemm_qkvp(GemmQKVP g) {
  const int z = blockIdx.z;
  if ((int)blockIdx.x >= g.Nblocks[z]) return;
  const __bf16* __restrict__ A = g.W[z];
  const __bf16* __restrict__ Bm = g.Act[z];
  const float* __restrict__ bias = g.bias[z];
  __bf16* __restrict__ Cout = g.out[z];
  constexpr int K = F_;
  __shared__ __bf16 As[128 * 32];
  __shared__ __bf16 Bs[128 * 32];
  const int tid = threadIdx.x;
  const int wave = tid >> 6, lane = tid & 63;
  const int mrow = lane & 15, quad = lane >> 4;
  const long m0 = (long)blockIdx.y * 128;  // f
  const long n0 = (long)blockIdx.x * 128;  // token
  const int wr = (wave >> 1) * 64, wc = (wave & 1) * 64;
  const int srow = lane >> 2;
  const int scol = (lane & 3) * 8;
  f32x4 acc[4][4] = {};
  for (int k0 = 0; k0 < K; k0 += 32) {
    if (k0) __syncthreads();
    for (int ph = 0; ph < 2; ++ph) {
      int rb = ph * 64 + wave * 16;
      async_cp16(A + (m0 + rb + srow) * (long)K + k0 + scol, As + rb * 32);
      async_cp16(Bm + (n0 + rb + srow) * (long)K + k0 + scol, Bs + rb * 32);
    }
    __syncthreads();
    bf16x8 af[4], bf[4];
    for (int i = 0; i < 4; i++) af[i] = *(const bf16x8*)&As[(wr + i * 16 + mrow) * 32 + quad * 8];
    for (int j = 0; j < 4; j++) bf[j] = *(const bf16x8*)&Bs[(wc + j * 16 + mrow) * 32 + quad * 8];
    for (int i = 0; i < 4; i++)
      for (int j = 0; j < 4; j++)
        acc[i][j] = __builtin_amdgcn_mfma_f32_16x16x32_bf16(af[i], bf[j], acc[i][j], 0, 0, 0);
  }
  for (int i = 0; i < 4; i++) {
    int frow = (int)m0 + wr + i * 16 + quad * 4;  // f, 4-aligned, same head across r
    float4 b4 = bias ? *(const float4*)&bias[frow] : make_float4(0.f, 0.f, 0.f, 0.f);
    int h = frow >> 6, dbase = frow & 63;
    for (int j = 0; j < 4; j++) {
      int token = (int)n0 + wc + j * 16 + mrow;
      int bb = token >> 11, tt = token & 2047;
      bf16x4 pk;
      pk[0] = (__bf16)(acc[i][j][0] + b4.x);
      pk[1] = (__bf16)(acc[i][j][1] + b4.y);
      pk[2] = (__bf16)(acc[i][j][2] + b4.z);
      pk[3] = (__bf16)(acc[i][j][3] + b4.w);
      *(bf16x4*)&Cout[(((long)(bb * H_ + h)) * T_ + tt) * DK_ + dbase] = pk;
    }
  }
}

// ---------------- plain C = A * B^T + bias, fp32 out (final projection) ----------------
__global__ __launch_bounds__(256) void gemm_out(
    const __bf16* __restrict__ A, const __bf16* __restrict__ Bm,
    float* __restrict__ Cout, const float* __restrict__ bias, int N, int K) {
  __shared__ __bf16 As[128 * 32];
  __shared__ __bf16 Bs[128 * 32];
  const int tid = threadIdx.x;
  const int wave = tid >> 6, lane = tid & 63;
  const int mrow = lane & 15, quad = lane >> 4;
  const long m0 = (long)blockIdx.y * 128, n0 = (long)blockIdx.x * 128;
  const int wr = (wave >> 1) * 64, wc = (wave & 1) * 64;
  const int srow = lane >> 2;
  const int scol = (lane & 3) * 8;
  f32x4 acc[4][4] = {};
  for (int k0 = 0; k0 < K; k0 += 32) {
    if (k0) __syncthreads();
    for (int ph = 0; ph < 2; ++ph) {
      int rb = ph * 64 + wave * 16;
      async_cp16(A + (m0 + rb + srow) * (long)K + k0 + scol, As + rb * 32);
      async_cp16(Bm + (n0 + rb + srow) * (long)K + k0 + scol, Bs + rb * 32);
    }
    __syncthreads();
    bf16x8 af[4], bf[4];
    for (int i = 0; i < 4; i++) af[i] = *(const bf16x8*)&As[(wr + i * 16 + mrow) * 32 + quad * 8];
    for (int j = 0; j < 4; j++) bf[j] = *(const bf16x8*)&Bs[(wc + j * 16 + mrow) * 32 + quad * 8];
    for (int i = 0; i < 4; i++)
      for (int j = 0; j < 4; j++)
        acc[i][j] = __builtin_amdgcn_mfma_f32_16x16x32_bf16(af[i], bf[j], acc[i][j], 0, 0, 0);
  }
  for (int i = 0; i < 4; i++) {
    int row = (int)m0 + wr + i * 16 + quad * 4;
    for (int j = 0; j < 4; j++) {
      int col = (int)n0 + wc + j * 16 + mrow;
      float bval = bias[col];
      for (int r = 0; r < 4; r++)
        Cout[(long)(row + r) * N + col] = acc[i][j][r] + bval;
    }
  }
}

// ---------------- prep: K' = K + P, biasC = (u.K + v.P)*SCALE_LOG2, Vt = V^T ----------------
__global__ __launch_bounds__(256) void prep(
    const __bf16* __restrict__ Ph, __bf16* __restrict__ Kh,
    const __bf16* __restrict__ Vh, __bf16* __restrict__ Vth,
    const float* __restrict__ u, const float* __restrict__ vb,
    float* __restrict__ biasC) {
  __shared__ __bf16 Vl[64 * 72];
  const int tc = blockIdx.x, h = blockIdx.y, b = blockIdx.z;
  const int tid = threadIdx.x;
  const int r4 = tid >> 2, c16 = (tid & 3) * 16;
  const long bh = b * H_ + h;
  const long kbase = (bh * T_ + tc * 64 + r4) * DK_ + c16;
  const long pbase = (((long)h) * T_ + tc * 64 + r4) * DK_ + c16;
  bf16x8 k0 = *(const bf16x8*)&Kh[kbase];
  bf16x8 k1 = *(const bf16x8*)&Kh[kbase + 8];
  bf16x8 p0 = *(const bf16x8*)&Ph[pbase];
  bf16x8 p1 = *(const bf16x8*)&Ph[pbase + 8];
  float4 u0 = *(const float4*)&u[h * 64 + c16];
  float4 u1 = *(const float4*)&u[h * 64 + c16 + 4];
  float4 u2 = *(const float4*)&u[h * 64 + c16 + 8];
  float4 u3 = *(const float4*)&u[h * 64 + c16 + 12];
  float4 v0 = *(const float4*)&vb[h * 64 + c16];
  float4 v1 = *(const float4*)&vb[h * 64 + c16 + 4];
  float4 v2 = *(const float4*)&vb[h * 64 + c16 + 8];
  float4 v3 = *(const float4*)&vb[h * 64 + c16 + 12];
  float s = 0.f;
  {
    const float uu[16] = {u0.x,u0.y,u0.z,u0.w,u1.x,u1.y,u1.z,u1.w,u2.x,u2.y,u2.z,u2.w,u3.x,u3.y,u3.z,u3.w};
    const float vv[16] = {v0.x,v0.y,v0.z,v0.w,v1.x,v1.y,v1.z,v1.w,v2.x,v2.y,v2.z,v2.w,v3.x,v3.y,v3.z,v3.w};
#pragma unroll
    for (int j = 0; j < 8; j++) {
      s += (float)k0[j] * uu[j] + (float)p0[j] * vv[j];
      s += (float)k1[j] * uu[8 + j] + (float)p1[j] * vv[8 + j];
    }
  }
  bf16x8 kp0, kp1;
#pragma unroll
  for (int j = 0; j < 8; j++) {
    kp0[j] = (__bf16)((float)k0[j] + (float)p0[j]);
    kp1[j] = (__bf16)((float)k1[j] + (float)p1[j]);
  }
  *(bf16x8*)&Kh[kbase] = kp0;
  *(bf16x8*)&Kh[kbase + 8] = kp1;
  s += __shfl_xor(s, 1);
  s += __shfl_xor(s, 2);
  if ((tid & 3) == 0) biasC[bh * T_ + tc * 64 + r4] = s * SCALE_LOG2;
  // V transpose via LDS
  const long vbase = (bh * T_ + tc * 64 + r4) * DK_ + c16;
  bf16x8 vv0 = *(const bf16x8*)&Vh[vbase];
  bf16x8 vv1 = *(const bf16x8*)&Vh[vbase + 8];
  *(bf16x8*)&Vl[r4 * 72 + c16] = vv0;
  *(bf16x8*)&Vl[r4 * 72 + c16 + 8] = vv1;
  __syncthreads();
  const int d4 = tid >> 2, tcol = (tid & 3) * 16;
  bf16x8 o0, o1;
#pragma unroll
  for (int j = 0; j < 8; j++) {
    o0[j] = Vl[(tcol + j) * 72 + d4];
    o1[j] = Vl[(tcol + 8 + j) * 72 + d4];
  }
  long obase = (bh * DK_ + d4) * T_ + tc * 64 + tcol;
  *(bf16x8*)&Vth[obase] = o0;
  *(bf16x8*)&Vth[obase + 8] = o1;
}

// ---------------- banded flash attention: key-split waves, no-max softmax ----------------
// Wave w owns a 32-key slice (all 64 q-rows) for QK+softmax; PV: wave w owns rows
// [16w,16w+16) over all staged keys. Q frags in registers; K frags direct from global.
template <int FULL>  // 1: 128-key step, 0: 64-key step (waves 0,1 only in QK phase)
__device__ __forceinline__ void attn_step2(
    int s0, long bh, int tid, int wave, int mrow, int quad,
    const __bf16* __restrict__ Kh, const __bf16* __restrict__ Vth,
    const float* __restrict__ Bp, const bf16x8 (&qf)[4][2],
    __bf16* Pl, __bf16* Vt, f32x4 accO[4], f32x4& accL) {
  __syncthreads();  // prev-step Pl/Vt readers done
  // stage V^T [64 x W] into Vt (row pad 136)
  if (FULL) {
#pragma unroll
    for (int p = 0; p < 4; ++p) {
      int idx = tid + p * 256;
      int row = idx >> 4, colg = (idx & 15) * 8;
      *(bf16x8*)&Vt[row * 136 + colg] =
          *(const bf16x8*)&Vth[(bh * DK_ + row) * T_ + s0 + colg];
    }
  } else {
#pragma unroll
    for (int p = 0; p < 2; ++p) {
      int idx = tid + p * 256;
      int row = idx >> 3, colg = (idx & 7) * 8;
      *(bf16x8*)&Vt[row * 136 + colg] =
          *(const bf16x8*)&Vth[(bh * DK_ + row) * T_ + s0 + colg];
    }
  }
  if (FULL || wave < 2) {
    const int krow = s0 + wave * 32;
    bf16x8 kf[2][2];
#pragma unroll
    for (int nt = 0; nt < 2; ++nt)
#pragma unroll
      for (int kh = 0; kh < 2; ++kh)
        kf[nt][kh] = *(const bf16x8*)&Kh[(bh * T_ + krow + nt * 16 + mrow) * DK_ + kh * 32 + quad * 8];
    float bias01[2] = {Bp[krow + mrow], Bp[krow + 16 + mrow]};
    f32x4 s[4][2];
#pragma unroll
    for (int mt = 0; mt < 4; ++mt)
#pragma unroll
      for (int nt = 0; nt < 2; ++nt) {
        f32x4 a = {0.f, 0.f, 0.f, 0.f};
        a = __builtin_amdgcn_mfma_f32_16x16x32_bf16(qf[mt][0], kf[nt][0], a, 0, 0, 0);
        a = __builtin_amdgcn_mfma_f32_16x16x32_bf16(qf[mt][1], kf[nt][1], a, 0, 0, 0);
        s[mt][nt] = a;
      }
#pragma unroll
    for (int mt = 0; mt < 4; ++mt)
#pragma unroll
      for (int nt = 0; nt < 2; ++nt)
#pragma unroll
        for (int r = 0; r < 4; ++r) {
          float p = __builtin_amdgcn_exp2f(s[mt][nt][r] * SCALE_LOG2 + bias01[nt]);
          Pl[(mt * 16 + quad * 4 + r) * 136 + wave * 32 + nt * 16 + mrow] = (__bf16)p;
        }
  }
  __syncthreads();  // Pl + Vt published
  constexpr int NKT = FULL ? 4 : 2;
  bf16x8 ones;
#pragma unroll
  for (int j = 0; j < 8; ++j) ones[j] = (__bf16)1.0f;
  bf16x8 ap[NKT];
#pragma unroll
  for (int kt = 0; kt < NKT; ++kt)
    ap[kt] = *(const bf16x8*)&Pl[(wave * 16 + mrow) * 136 + kt * 32 + quad * 8];
#pragma unroll
  for (int kt = 0; kt < NKT; ++kt) {
    accL = __builtin_amdgcn_mfma_f32_16x16x32_bf16(ap[kt], ones, accL, 0, 0, 0);
#pragma unroll
    for (int nt = 0; nt < 4; ++nt) {
      bf16x8 bv = *(const bf16x8*)&Vt[(nt * 16 + mrow) * 136 + kt * 32 + quad * 8];
      accO[nt] = __builtin_amdgcn_mfma_f32_16x16x32_bf16(ap[kt], bv, accO[nt], 0, 0, 0);
    }
  }
}

__global__ __launch_bounds__(256) void attn_banded(
    const __bf16* __restrict__ Qh, const __bf16* __restrict__ Kh,
    const __bf16* __restrict__ Vth, const float* __restrict__ biasC,
    __bf16* __restrict__ X) {
  __shared__ __bf16 Pl[64 * 136];  // 17408 B
  __shared__ __bf16 Vt[64 * 136];  // 17408 B -> 34816 total
  const int qc = blockIdx.x, h = blockIdx.y, b = blockIdx.z;
  const int tid = threadIdx.x, wave = tid >> 6, lane = tid & 63;
  const int mrow = lane & 15, quad = lane >> 4;
  const long bh = b * H_ + h;
  const int span = (qc >= 16 ? 17 : qc + 1);
  const int s_lo = (qc + 1 - span) * 64, s_hi = (qc + 1) * 64;
  const float* Bp = biasC + bh * T_;
  // Q fragments in registers for the whole band
  bf16x8 qf[4][2];
#pragma unroll
  for (int mt = 0; mt < 4; ++mt)
#pragma unroll
    for (int kh = 0; kh < 2; ++kh)
      qf[mt][kh] = *(const bf16x8*)&Qh[(bh * T_ + qc * 64 + mt * 16 + mrow) * DK_ + kh * 32 + quad * 8];
  f32x4 accO[4] = {};
  f32x4 accL = {0.f, 0.f, 0.f, 0.f};
  int s0 = s_lo;
  if (span & 1) {
    attn_step2<0>(s0, bh, tid, wave, mrow, quad, Kh, Vth, Bp, qf, Pl, Vt, accO, accL);
    s0 += 64;
  }
  for (; s0 < s_hi; s0 += 128)
    attn_step2<1>(s0, bh, tid, wave, mrow, quad, Kh, Vth, Bp, qf, Pl, Vt, accO, accL);
#pragma unroll
  for (int r = 0; r < 4; ++r) {
    float inv = 1.0f / accL[r];
    int t = qc * 64 + wave * 16 + quad * 4 + r;
#pragma unroll
    for (int nt = 0; nt < 4; ++nt)
      X[((long)(b * T_ + t) * H_ + h) * DK_ + nt * 16 + mrow] = (__bf16)(accO[nt][r] * inv);
  }
}

extern "C" void kernel_launch(void* const* d_in, const int* in_sizes, int n_in,
                              void* d_out, int out_size, void* d_ws, size_t ws_size,
                              hipStream_t stream) {
  (void)in_sizes; (void)n_in; (void)out_size; (void)ws_size;
  const float* query = (const float*)d_in[0];
  const float* key   = (const float*)d_in[1];
  const float* value = (const float*)d_in[2];
  const float* pos   = (const float*)d_in[3];
  // d_in[4] = mask: band structure computed analytically
  const float* Wq = (const float*)d_in[5];
  const float* bq = (const float*)d_in[6];
  const float* Wk = (const float*)d_in[7];
  const float* bk = (const float*)d_in[8];
  const float* Wv = (const float*)d_in[9];
  const float* bv = (const float*)d_in[10];
  const float* Wp = (const float*)d_in[11];
  const float* Wo = (const float*)d_in[12];
  const float* bo = (const float*)d_in[13];
  const float* pu = (const float*)d_in[14];
  const float* pvb = (const float*)d_in[15];

  const long NQ = (long)B_ * T_ * F_;  // 8388608
  const long NP = (long)T_ * F_;       // 2097152
  const long NW = (long)F_ * F_;       // 1048576
  char* ws = (char*)d_ws;
  __bf16* qb  = (__bf16*)ws; ws += NQ * 2;
  __bf16* kb  = (__bf16*)ws; ws += NQ * 2;
  __bf16* vbm = (__bf16*)ws; ws += NQ * 2;
  __bf16* pb  = (__bf16*)ws; ws += NP * 2;
  __bf16* wqb = (__bf16*)ws; ws += NW * 2;
  __bf16* wkb = (__bf16*)ws; ws += NW * 2;
  __bf16* wvb = (__bf16*)ws; ws += NW * 2;
  __bf16* wpb = (__bf16*)ws; ws += NW * 2;
  __bf16* wob = (__bf16*)ws; ws += NW * 2;
  __bf16* Qh  = (__bf16*)ws; ws += NQ * 2;
  __bf16* Kh  = (__bf16*)ws; ws += NQ * 2;
  __bf16* Vh  = (__bf16*)ws; ws += NQ * 2;
  __bf16* Ph  = (__bf16*)ws; ws += NP * 2;
  float*  biasC = (float*)ws; ws += (long)B_ * H_ * T_ * 4;
  __bf16* Vth = kb;  // alias: kb dead after K-GEMM
  __bf16* Xb  = qb;  // alias: qb dead after Q-GEMM

  {
    CvtArgs ca;
    ca.src[0] = query; ca.dst[0] = qb;  ca.n[0] = (int)NQ;
    ca.src[1] = key;   ca.dst[1] = kb;  ca.n[1] = (int)NQ;
    ca.src[2] = value; ca.dst[2] = vbm; ca.n[2] = (int)NQ;
    ca.src[3] = pos;   ca.dst[3] = pb;  ca.n[3] = (int)NP;
    ca.src[4] = Wq;    ca.dst[4] = wqb; ca.n[4] = (int)NW;
    ca.src[5] = Wk;    ca.dst[5] = wkb; ca.n[5] = (int)NW;
    ca.src[6] = Wv;    ca.dst[6] = wvb; ca.n[6] = (int)NW;
    ca.src[7] = Wp;    ca.dst[7] = wpb; ca.n[7] = (int)NW;
    ca.src[8] = Wo;    ca.dst[8] = wob; ca.n[8] = (int)NW;
    cvt_all<<<dim3(4096, 9), 256, 0, stream>>>(ca);
  }
  {
    GemmQKVP g;
    g.W[0] = wqb; g.Act[0] = qb;  g.bias[0] = bq;      g.out[0] = Qh; g.Nblocks[0] = 64;
    g.W[1] = wkb; g.Act[1] = kb;  g.bias[1] = bk;      g.out[1] = Kh; g.Nblocks[1] = 64;
    g.W[2] = wvb; g.Act[2] = vbm; g.bias[2] = bv;      g.out[2] = Vh; g.Nblocks[2] = 64;
    g.W[3] = wpb; g.Act[3] = pb;  g.bias[3] = nullptr; g.out[3] = Ph; g.Nblocks[3] = 16;
    gemm_qkvp<<<dim3(64, 8, 4), 256, 0, stream>>>(g);
  }
  prep<<<dim3(32, 16, 4), 256, 0, stream>>>(Ph, Kh, Vh, Vth, pu, pvb, biasC);
  attn_banded<<<dim3(32, 16, 4), 256, 0, stream>>>(Qh, Kh, Vth, biasC, Xb);
  gemm_out<<<dim3(8, 64), 256, 0, stream>>>(Xb, wob, (float*)d_out, bo, F_, F_);
}